// Round 16
// baseline (130.750 us; speedup 1.0000x reference)
//
#include <hip/hip_runtime.h>
#include <hip/hip_bf16.h>
#include <stdint.h>

// ---------------------------------------------------------------------------
// QNN forward:
//   angles = x@W^T + b                                  (embed blocks of k_main)
//   E[b][i] = prod_w cs[w][bit_{9-w}(i)]   (product state after RY embedding)
//   Rows 0..783 of the fixed circuit unitary U, via ADJOINT simulation:
//     k_prep: register-unrolled GF(2) plan + bank-uniform jtab (r14, ~3us).
//     k_main blocks 0..783: block p simulates U^dag|p> (100 quad passes over an
//             8KB LDS state, 256 thr, one s_barrier per pass; j from jtab),
//             writes Bt rows 2p/2p+1 directly.  [TLP-bound: keep 784 blocks]
//     k_main blocks 784..8975: embed rows (grid filler).
//   out[b][p] = clip(|amp|^2 * 784, 0, 1)
//     -> one f16 MFMA GEMM C[8192][1664] = E @ Bt^T: m201-port 8-PHASE
//        schedule, 256x256 tile, BK=64, 8 waves (2M x 4N, INTERLEAVED row/col
//        group ownership so half-tile usage is phase-determined), 128KB LDS
//        (2 bufs x 4 halves x [128][64]), per phase {12 ds_read_b128 ||
//        stage 1 half} -> barrier -> 16 MFMA -> [p3: vmcnt(4)] -> barrier.
//        Stage ledger (slot-reuse audited): (T,0)->B-hi(T+1), (T,1)->A-hi(T+1),
//        (T,2)->A-lo(T+2), (T,3)->B-lo(T+2); vmcnt(4) once/tile, 0 only @T=14.
//        T2 swizzle, |.|^2 epilogue via shfl_xor(1), XCD-swizzled grid.
// ---------------------------------------------------------------------------

#define NWIRES  10
#define DIM     1024
#define NLAYERS 20
#define NGATES  200
#define NPASS   100
#define PIXELS  784
#define BATCH   8192

typedef _Float16 f16;
typedef _Float16 f16x8 __attribute__((ext_vector_type(8)));
typedef float    f32x4 __attribute__((ext_vector_type(4)));
typedef float    f32x2 __attribute__((ext_vector_type(2)));

typedef const __attribute__((address_space(1))) void* gas1_t;
typedef __attribute__((address_space(3))) void*       las3_t;

__device__ __forceinline__ void gload_lds16(const void* g, void* l) {
  __builtin_amdgcn_global_load_lds((gas1_t)g, (las3_t)l, 16, 0, 0);
}

// ---------------------------------------------------------------------------
// Kernel 1: ADJOINT plan precompute (1 block).  (r14 verbatim)
// ---------------------------------------------------------------------------
__global__ __launch_bounds__(256) void k_prep(const float* __restrict__ qw,
                                              float* __restrict__ plan_mat,
                                              unsigned* __restrict__ plan_idx,
                                              unsigned* __restrict__ plan_final,
                                              unsigned* __restrict__ jtab) {
  __shared__ float    gm[NGATES][8];     // adjoint Rot matrices (complex 2x2)
  __shared__ unsigned shb[NPASS * 8];    // per-pass ordered kernel basis
  __shared__ unsigned shr[NPASS * 8];    // per-pass remainder scratch (LDS)
  __shared__ unsigned pp[NPASS][4];      // u1,u2,b1,b2 per pass
  const int tid = threadIdx.x;

  // Rot(phi,th,om)^dag entries:
  //   a00 = e^{+i(phi+om)/2} c    a01 = e^{+i(phi-om)/2} s
  //   a10 = -e^{-i(phi-om)/2} s   a11 = e^{-i(phi+om)/2} c
  if (tid < NGATES) {
    float phi = qw[tid * 3 + 0], th = qw[tid * 3 + 1], om = qw[tid * 3 + 2];
    float s, c, sa, ca, sb, cb;
    sincosf(0.5f * th, &s, &c);
    sincosf(0.5f * (phi + om), &sa, &ca);
    sincosf(0.5f * (phi - om), &sb, &cb);
    gm[tid][0] = ca * c;  gm[tid][1] = sa * c;    // a00
    gm[tid][2] = cb * s;  gm[tid][3] = sb * s;    // a01
    gm[tid][4] = -cb * s; gm[tid][5] = sb * s;    // a10
    gm[tid][6] = ca * c;  gm[tid][7] = -sa * c;   // a11
  }
  __syncthreads();

  // ---- phase A: GF(2) evolution, fully unrolled -> registers (fast) ----
  if (tid == 0) {
    unsigned rA[NWIRES], ic[NWIRES];
#pragma unroll
    for (int i = 0; i < NWIRES; i++) { rA[i] = 1u << i; ic[i] = 1u << i; }
#pragma unroll
    for (int lrev = 0; lrev < NLAYERS; lrev++) {
      const int l = NLAYERS - 1 - lrev;
      const int r = (l % (NWIRES - 1)) + 1;
      // inverse ring: same CNOTs, applied w = 9 .. 0
#pragma unroll
      for (int w = NWIRES - 1; w >= 0; w--) {
        const int t = (w + r) % NWIRES;
        rA[9 - t] ^= rA[9 - w];
        ic[9 - w] ^= ic[9 - t];
      }
#pragma unroll
      for (int s = 0; s < 5; s++) {
        const int p1 = 9 - 2 * s, p2 = 8 - 2 * s;
        unsigned u1 = rA[p1], u2 = rA[p2];
        unsigned m1 = ic[p1], m2 = ic[p2];
        // 2-row GF(2) elimination to echelon (b1 in u1 only, b2 in u2 only)
        unsigned b1 = u1 & (0u - u1);
        if (u2 & b1) u2 ^= u1;
        unsigned b2 = u2 & (0u - u2);
        if (u1 & b2) u1 ^= u2;
        const int pid = lrev * 5 + s;
        pp[pid][0] = u1; pp[pid][1] = u2;
        pp[pid][2] = b1; pp[pid][3] = b2;
        plan_idx[pid * 8 + 6] = m1;      // k_main reads P[6], P[7] only
        plan_idx[pid * 8 + 7] = m2;
      }
    }
#pragma unroll
    for (int p = 0; p < NWIRES; p++) plan_final[p] = ic[p];
  } else if (tid >= 100 && tid < 200) {
    // kron matrices in parallel with phase A (needs only gm)
    int t = tid - 100;                 // pass index
    int lrev = t / 5, s = t % 5;
    int l = NLAYERS - 1 - lrev;
    int g1 = l * NWIRES + 2 * s, g2 = g1 + 1;
    float* K = plan_mat + (size_t)t * 64;
#pragma unroll
    for (int r = 0; r < 4; r++) {
#pragma unroll
      for (int c = 0; c < 4; c++) {
        int r1 = r >> 1, c1 = c >> 1, r2 = r & 1, c2 = c & 1;
        float ar = gm[g1][(r1 * 2 + c1) * 2], ai = gm[g1][(r1 * 2 + c1) * 2 + 1];
        float br = gm[g2][(r2 * 2 + c2) * 2], bi = gm[g2][(r2 * 2 + c2) * 2 + 1];
        float kr = ar * br - ai * bi;
        float ki = ar * bi + ai * br;
        float* e = K + (r * 4 + c) * 4;
        e[0] = kr; e[1] = kr; e[2] = -ki; e[3] = ki;   // packed for pk-FMA
      }
    }
  }
  __syncthreads();

  // ---- phase B: bank-uniform basis per pass (100 parallel threads) ----
  if (tid < NPASS) {
    const int pid = tid;
    const unsigned u1 = pp[pid][0], u2 = pp[pid][1];
    const unsigned b1 = pp[pid][2], b2 = pp[pid][3];
    unsigned echPack = 0;              // 4 x 8-bit reduced nibbles
    int cnt = 0, nrem = 0;
    for (int f = 0; f < NWIRES; f++) {
      unsigned ef = 1u << f;
      if (ef == b1 || ef == b2) continue;
      unsigned v = ef ^ (((u1 >> f) & 1u) ? b1 : 0u)
                      ^ (((u2 >> f) & 1u) ? b2 : 0u);
      unsigned n = v & 15u;
#pragma unroll
      for (int rep = 0; rep < 4; rep++) {
#pragma unroll
        for (int k2 = 0; k2 < 4; k2++) {
          unsigned h = (echPack >> (8 * k2)) & 255u;
          if (h) {
            unsigned hb = 0x80000000u >> __clz(h);
            if (n & hb) n ^= h;
          }
        }
      }
      if (n && cnt < 4) {
        echPack |= n << (8 * cnt);
        shb[pid * 8 + cnt] = v;
        cnt++;
      } else {
        shr[pid * 8 + nrem] = v;
        nrem++;
      }
    }
    for (int i = 0; i < nrem; i++) shb[pid * 8 + cnt + i] = shr[pid * 8 + i];
  }
  __syncthreads();

  // ---- phase C: jtab[t][tid] = XOR-select of the ordered basis ----
  for (int t = 0; t < NPASS; t++) {
    unsigned j = 0;
#pragma unroll
    for (int b = 0; b < 8; b++)
      if ((tid >> b) & 1) j ^= shb[t * 8 + b];
    jtab[t * 256 + tid] = j;
  }
}

// ---------------------------------------------------------------------------
// Kernel 2 (fused): blocks 0..783 = usim column p; blocks 784.. = embed rows.
// (r14 verbatim)
// ---------------------------------------------------------------------------
__global__ __launch_bounds__(256) void k_main(const float* __restrict__ plan_mat,
                                              const unsigned* __restrict__ plan_idx,
                                              const unsigned* __restrict__ plan_final,
                                              const unsigned* __restrict__ jtab,
                                              const float* __restrict__ x,
                                              const float* __restrict__ W,
                                              const float* __restrict__ bias,
                                              f16* __restrict__ E,
                                              f16* __restrict__ Bt) {
  __shared__ f32x2 st[DIM];          // usim state (8 KB)
  __shared__ float part[4][NWIRES];  // embed partials
  __shared__ float csh[NWIRES][2];   // embed cos/sin

  const int tid = threadIdx.x;

  if (blockIdx.x < PIXELS) {
    // ---------------- usim: simulate U^dag |col> ----------------
    const int col = blockIdx.x;

    for (int i = tid; i < DIM; i += 256)
      st[i] = (f32x2){i == col ? 1.f : 0.f, 0.f};

    unsigned jn = jtab[tid];           // prefetch pass 0's quad base
    __syncthreads();

    for (int t = 0; t < NPASS; t++) {
      const unsigned* P = plan_idx + (size_t)t * 8;
      const unsigned m1 = P[6], m2 = P[7];
      const f32x4* Kp = (const f32x4*)(plan_mat + (size_t)t * 64);

      const unsigned j = jn;
      if (t + 1 < NPASS) jn = jtab[(t + 1) * 256 + tid];  // hide L2 latency

      f32x2 v0 = st[j];
      f32x2 v1 = st[j ^ m2];
      f32x2 v2 = st[j ^ m1];
      f32x2 v3 = st[j ^ m1 ^ m2];
      f32x2 w0 = {v0.y, v0.x}, w1 = {v1.y, v1.x};
      f32x2 w2 = {v2.y, v2.x}, w3 = {v3.y, v3.x};

      f32x2 r0 = {0.f, 0.f}, r1 = {0.f, 0.f}, r2 = {0.f, 0.f}, r3 = {0.f, 0.f};
      // Kp[e] = (kr, kr, -ki, ki):  acc += (kr,kr)*v ; acc += (-ki,ki)*swap(v)
#define CM(rr, e, vv, ww)                         \
      { f32x4 kk = Kp[e];                         \
        rr += (f32x2){kk.x, kk.y} * (vv);         \
        rr += (f32x2){kk.z, kk.w} * (ww); }
      CM(r0, 0, v0, w0)  CM(r0, 1, v1, w1)  CM(r0, 2, v2, w2)  CM(r0, 3, v3, w3)
      CM(r1, 4, v0, w0)  CM(r1, 5, v1, w1)  CM(r1, 6, v2, w2)  CM(r1, 7, v3, w3)
      CM(r2, 8, v0, w0)  CM(r2, 9, v1, w1)  CM(r2, 10, v2, w2) CM(r2, 11, v3, w3)
      CM(r3, 12, v0, w0) CM(r3, 13, v1, w1) CM(r3, 14, v2, w2) CM(r3, 15, v3, w3)
#undef CM

      // In-place write of the SAME quad this thread read: disjoint across
      // threads, so no intra-pass hazard; one barrier separates passes.
      st[j]           = r0;
      st[j ^ m2]      = r1;
      st[j ^ m1]      = r2;
      st[j ^ m1 ^ m2] = r3;
      __syncthreads();
    }

    // logical amplitude i lives at storage j = XOR of inv columns of set bits;
    // U[p][i] = conj(st[j]).
    unsigned invl[NWIRES];
#pragma unroll
    for (int p = 0; p < NWIRES; p++) invl[p] = plan_final[p];

    __align__(8) f16 re4[4], im4[4];
#pragma unroll
    for (int u = 0; u < 4; u++) {
      int i = tid * 4 + u;
      unsigned j = 0;
#pragma unroll
      for (int p = 0; p < NWIRES; p++)
        if ((i >> p) & 1) j ^= invl[p];
      f32x2 v = st[j];
      re4[u] = (f16)v.x;
      im4[u] = (f16)(-v.y);
    }
    *(uint2*)(&Bt[(size_t)(2 * col) * DIM + tid * 4])     = *(const uint2*)re4;
    *(uint2*)(&Bt[(size_t)(2 * col + 1) * DIM + tid * 4]) = *(const uint2*)im4;
    return;
  }

  // ---------------- embed: linear layer + RY product state ----------------
  const int b = blockIdx.x - PIXELS;
  const float* xr = x + (size_t)b * PIXELS;

  float acc[NWIRES];
#pragma unroll
  for (int w = 0; w < NWIRES; w++) acc[w] = 0.f;

  for (int k = tid; k < PIXELS; k += 256) {
    float xv = xr[k];
#pragma unroll
    for (int w = 0; w < NWIRES; w++) acc[w] = fmaf(xv, W[w * PIXELS + k], acc[w]);
  }

#pragma unroll
  for (int w = 0; w < NWIRES; w++) {
    float v = acc[w];
#pragma unroll
    for (int off = 32; off > 0; off >>= 1) v += __shfl_xor(v, off, 64);
    acc[w] = v;
  }

  const int wv = tid >> 6, ln = tid & 63;
  if (ln == 0) {
#pragma unroll
    for (int w = 0; w < NWIRES; w++) part[wv][w] = acc[w];
  }
  __syncthreads();
  if (tid < NWIRES) {
    float a = part[0][tid] + part[1][tid] + part[2][tid] + part[3][tid] + bias[tid];
    float s, c;
    sincosf(0.5f * a, &s, &c);
    csh[tid][0] = c;
    csh[tid][1] = s;
  }
  __syncthreads();

  __align__(8) f16 e4[4];
#pragma unroll
  for (int u = 0; u < 4; u++) {
    int i = tid * 4 + u;
    float pr = 1.f;
#pragma unroll
    for (int w = 0; w < NWIRES; w++) pr *= csh[w][(i >> (9 - w)) & 1];
    e4[u] = (f16)pr;
  }
  *(uint2*)(&E[(size_t)b * DIM + tid * 4]) = *(const uint2*)e4;
}

// ---------------------------------------------------------------------------
// Kernel 3: C = E[8192][1024] @ Bt^T, f16 MFMA 16x16x32 — m201 8-phase port.
// 256x256 tile, BK=64, 512 threads (8 waves 2M x 4N, INTERLEAVED groups:
// wave wm owns row groups {wm, wm+2, ...}; wn owns col groups {wn, wn+4, ...}
// so A-lo is used at phases 0,1; A-hi at 2,3; B-lo at 0,2; B-hi at 1,3).
// LDS: lds[buf*4 + half][128*64], half: 0=A-lo 1=A-hi 2=B-lo 3=B-hi.
// Phase (T,p): 12 ds_read_b128 (quadrant) ; stage one half ; barrier ;
//   16 MFMA (setprio) ; [p==3: vmcnt(4), T==14: vmcnt(0)] ; barrier.
// Stage ledger: (T,0)->B-hi(T+1), (T,1)->A-hi(T+1), (T,2)->A-lo(T+2),
//   (T,3)->B-lo(T+2); every slot write strictly follows its last reader's
//   end-barrier; vmcnt(4)@(T,3) lands tile T+1 completely (2 halves in
//   flight). Prologue: tile0 + A-lo/B-lo of tile1, vmcnt(4).
// T2 swizzle: slot ^= row&7 on stage source + ds_read. XCD swizzle 224=8x28.
// ---------------------------------------------------------------------------
__global__ __launch_bounds__(512, 2) void k_gemm(const f16* __restrict__ E,
                                                 const f16* __restrict__ Bt,
                                                 float* __restrict__ out) {
  __shared__ __align__(16) f16 lds[8][128 * 64];   // 128 KB

  const int tid = threadIdx.x;                     // 0..511
  const int wid = tid >> 6, ln = tid & 63;
  const int wm = wid >> 2, wn = wid & 3;           // 2M x 4N

  const int bid = blockIdx.x;                      // 0..223 (32 mt x 7 nt)
  const int swz = (bid & 7) * 28 + (bid >> 3);     // XCD-contiguous chunks
  const int mt  = swz % 32, nt = swz / 32;
  const int m0  = mt * 256;
  const int n0  = nt * 256;

  f32x4 acc[8][4];
#pragma unroll
  for (int a = 0; a < 8; a++)
#pragma unroll
    for (int q = 0; q < 4; q++) acc[a][q] = (f32x4){0.f, 0.f, 0.f, 0.f};

  // swizzled ds_read offsets within a [128][64] half (same for either half)
  int offA[4][2], offB[2][2];
#pragma unroll
  for (int mi = 0; mi < 4; mi++)
#pragma unroll
    for (int kk = 0; kk < 2; kk++) {
      int r = (mi * 2 + wm) * 16 + (ln & 15);
      offA[mi][kk] = r * 64 + (((kk * 4 + (ln >> 4)) ^ (r & 7)) * 8);
    }
#pragma unroll
  for (int ni = 0; ni < 2; ni++)
#pragma unroll
    for (int kk = 0; kk < 2; kk++) {
      int r = (ni * 4 + wn) * 16 + (ln & 15);
      offB[ni][kk] = r * 64 + (((kk * 4 + (ln >> 4)) ^ (r & 7)) * 8);
    }

  // stage half `half_id` (0=A-lo 1=A-hi 2=B-lo 3=B-hi) of tile `tile`:
  // 2 gload_lds/thread; linear LDS dest, inverse-swizzled global source.
  auto stage = [&](int tile, int half_id) {
    const int buf = tile & 1;
    const f16* src = (half_id < 2) ? E : Bt;
    const int rbase = ((half_id < 2) ? m0 : n0) + ((half_id & 1) ? 128 : 0);
    f16* dst = &lds[buf * 4 + half_id][0];
#pragma unroll
    for (int r2 = 0; r2 < 2; r2++) {
      int u   = r2 * 512 + tid;               // 16B unit, 0..1023
      int row = u >> 3;
      int c8  = (u & 7) ^ (row & 7);          // inverse-swizzled source slot
      gload_lds16((const char*)src +
                      ((size_t)(rbase + row) * 1024 + tile * 64 + c8 * 8) * 2,
                  (char*)dst + (size_t)u * 16);
    }
  };

#define PH(T, p)                                                              \
  {                                                                           \
    const int buf = (T) & 1;                                                  \
    const int qm = (p) >> 1, qn = (p) & 1;                                    \
    const f16* A_ = &lds[buf * 4 + qm][0];                                    \
    const f16* B_ = &lds[buf * 4 + 2 + qn][0];                                \
    f16x8 af[4][2], bf[2][2];                                                 \
    _Pragma("unroll")                                                         \
    for (int kk = 0; kk < 2; kk++) {                                          \
      _Pragma("unroll")                                                       \
      for (int mi = 0; mi < 4; mi++)                                          \
        af[mi][kk] = *(const f16x8*)&A_[offA[mi][kk]];                        \
      _Pragma("unroll")                                                       \
      for (int ni = 0; ni < 2; ni++)                                          \
        bf[ni][kk] = *(const f16x8*)&B_[offB[ni][kk]];                        \
    }                                                                         \
    if ((p) == 0)      { if ((T) <= 14) stage((T) + 1, 3); }                  \
    else if ((p) == 1) { if ((T) <= 14) stage((T) + 1, 1); }                  \
    else if ((p) == 2) { if ((T) <= 13) stage((T) + 2, 0); }                  \
    else               { if ((T) <= 13) stage((T) + 2, 2); }                  \
    __builtin_amdgcn_s_barrier();                                             \
    asm volatile("s_waitcnt lgkmcnt(0)" ::: "memory");                        \
    __builtin_amdgcn_s_setprio(1);                                            \
    _Pragma("unroll")                                                         \
    for (int kk = 0; kk < 2; kk++)                                            \
      _Pragma("unroll")                                                       \
      for (int mi = 0; mi < 4; mi++)                                          \
        _Pragma("unroll")                                                     \
        for (int ni = 0; ni < 2; ni++)                                        \
          acc[qm * 4 + mi][qn * 2 + ni] =                                     \
              __builtin_amdgcn_mfma_f32_16x16x32_f16(                         \
                  af[mi][kk], bf[ni][kk], acc[qm * 4 + mi][qn * 2 + ni],      \
                  0, 0, 0);                                                   \
    __builtin_amdgcn_s_setprio(0);                                            \
    if ((p) == 3) {                                                           \
      if ((T) <= 13)      { asm volatile("s_waitcnt vmcnt(4)" ::: "memory"); }\
      else if ((T) == 14) { asm volatile("s_waitcnt vmcnt(0)" ::: "memory"); }\
    }                                                                         \
    __builtin_amdgcn_s_barrier();                                             \
  }

  // prologue: tile0 complete + tile1 {A-lo, B-lo}; vmcnt(4) lands tile0.
  stage(0, 0); stage(0, 2); stage(0, 3); stage(0, 1);
  stage(1, 0); stage(1, 2);
  asm volatile("s_waitcnt vmcnt(4)" ::: "memory");
  __builtin_amdgcn_s_barrier();

  for (int T = 0; T < 16; T++) {
    PH(T, 0)
    PH(T, 1)
    PH(T, 2)
    PH(T, 3)
  }
#undef PH

  // epilogue: n even = Re, n odd = Im (adjacent lanes); p = n>>1
#pragma unroll
  for (int mig = 0; mig < 8; mig++) {
#pragma unroll
    for (int nig = 0; nig < 4; nig++) {
      int gR = (mig >> 2) * 8 + (mig & 3) * 2 + wm;     // row group 0..15
      int gC = (nig >> 1) * 8 + (nig & 1) * 4 + wn;     // col group 0..15
      int n  = n0 + gC * 16 + (ln & 15);
      int p  = n >> 1;
      bool even = (ln & 1) == 0;
#pragma unroll
      for (int r = 0; r < 4; r++) {
        float v = acc[mig][nig][r];
        float o = __shfl_xor(v, 1, 64);
        if (even && p < PIXELS) {
          int m = m0 + gR * 16 + (ln >> 4) * 4 + r;
          float s2 = (v * v + o * o) * (float)PIXELS;
          out[(size_t)m * PIXELS + p] = fminf(fmaxf(s2, 0.f), 1.f);
        }
      }
    }
  }
}

// ---------------------------------------------------------------------------
extern "C" void kernel_launch(void* const* d_in, const int* in_sizes, int n_in,
                              void* d_out, int out_size, void* d_ws, size_t ws_size,
                              hipStream_t stream) {
  const float* x    = (const float*)d_in[0];
  const float* W    = (const float*)d_in[1];
  const float* bias = (const float*)d_in[2];
  const float* qw   = (const float*)d_in[3];
  float* out        = (float*)d_out;

  char* ws = (char*)d_ws;
  f16* E  = (f16*)(ws);                                   // 16 MiB: [8192][1024]
  f16* Bt = (f16*)(ws + (size_t)16 * 1024 * 1024);        //  4 MiB: [2048][1024]
  float*    plan_mat   = (float*)(ws + (size_t)20 * 1024 * 1024);            // 25.6 KB
  unsigned* plan_idx   = (unsigned*)(ws + (size_t)20 * 1024 * 1024 + 65536); //  3.2 KB
  unsigned* plan_final = (unsigned*)(ws + (size_t)20 * 1024 * 1024 + 131072);//  40 B
  unsigned* jtab       = (unsigned*)(ws + (size_t)20 * 1024 * 1024 + 196608);// 102.4 KB

  k_prep<<<dim3(1), dim3(256), 0, stream>>>(qw, plan_mat, plan_idx, plan_final,
                                            jtab);
  k_main<<<dim3(PIXELS + BATCH), dim3(256), 0, stream>>>(plan_mat, plan_idx,
                                                         plan_final, jtab,
                                                         x, W, bias, E, Bt);
  k_gemm<<<dim3(224), dim3(512), 0, stream>>>(E, Bt, out);
}

// Round 17
// 125.712 us; speedup vs baseline: 1.0401x; 1.0401x over previous
//
#include <hip/hip_runtime.h>
#include <hip/hip_bf16.h>
#include <stdint.h>

// ---------------------------------------------------------------------------
// QNN forward:
//   angles = x@W^T + b                                  (embed blocks of k_main)
//   E[b][i] = prod_w cs[w][bit_{9-w}(i)]   (product state after RY embedding)
//   Rows 0..783 of the fixed circuit unitary U, via ADJOINT simulation:
//     k_prep: register-unrolled GF(2) plan + bank-uniform jtab (r14, ~3us).
//     k_main blocks 0..783: block p simulates U^dag|p> (100 quad passes over an
//             8KB LDS state, 256 thr, one s_barrier per pass; j from jtab),
//             writes Bt rows 2p/2p+1 directly.  [TLP-bound: keep 784 blocks]
//     k_main blocks 784..8975: embed rows (grid filler).
//   out[b][p] = clip(|amp|^2 * 784, 0, 1)
//     -> one f16 MFMA GEMM C[8192][1664] = E @ Bt^T: 8-phase m201 port with
//        REGISTER-CACHED fragments (r16 re-read defect fixed: 24 unique
//        ds_read_b128 per K-tile per wave instead of 48 — p0 reads af+bfl,
//        p1 reads bfh, p2 re-reads af from A-hi, p3 reads nothing).
//        Same stage ledger as r16 (slot-reuse audited, vmcnt(4) once/tile).
//        T2 swizzle, |.|^2 epilogue via shfl_xor(1), XCD-swizzled grid.
// ---------------------------------------------------------------------------

#define NWIRES  10
#define DIM     1024
#define NLAYERS 20
#define NGATES  200
#define NPASS   100
#define PIXELS  784
#define BATCH   8192

typedef _Float16 f16;
typedef _Float16 f16x8 __attribute__((ext_vector_type(8)));
typedef float    f32x4 __attribute__((ext_vector_type(4)));
typedef float    f32x2 __attribute__((ext_vector_type(2)));

typedef const __attribute__((address_space(1))) void* gas1_t;
typedef __attribute__((address_space(3))) void*       las3_t;

__device__ __forceinline__ void gload_lds16(const void* g, void* l) {
  __builtin_amdgcn_global_load_lds((gas1_t)g, (las3_t)l, 16, 0, 0);
}

// ---------------------------------------------------------------------------
// Kernel 1: ADJOINT plan precompute (1 block).  (r14 verbatim)
// ---------------------------------------------------------------------------
__global__ __launch_bounds__(256) void k_prep(const float* __restrict__ qw,
                                              float* __restrict__ plan_mat,
                                              unsigned* __restrict__ plan_idx,
                                              unsigned* __restrict__ plan_final,
                                              unsigned* __restrict__ jtab) {
  __shared__ float    gm[NGATES][8];     // adjoint Rot matrices (complex 2x2)
  __shared__ unsigned shb[NPASS * 8];    // per-pass ordered kernel basis
  __shared__ unsigned shr[NPASS * 8];    // per-pass remainder scratch (LDS)
  __shared__ unsigned pp[NPASS][4];      // u1,u2,b1,b2 per pass
  const int tid = threadIdx.x;

  // Rot(phi,th,om)^dag entries:
  //   a00 = e^{+i(phi+om)/2} c    a01 = e^{+i(phi-om)/2} s
  //   a10 = -e^{-i(phi-om)/2} s   a11 = e^{-i(phi+om)/2} c
  if (tid < NGATES) {
    float phi = qw[tid * 3 + 0], th = qw[tid * 3 + 1], om = qw[tid * 3 + 2];
    float s, c, sa, ca, sb, cb;
    sincosf(0.5f * th, &s, &c);
    sincosf(0.5f * (phi + om), &sa, &ca);
    sincosf(0.5f * (phi - om), &sb, &cb);
    gm[tid][0] = ca * c;  gm[tid][1] = sa * c;    // a00
    gm[tid][2] = cb * s;  gm[tid][3] = sb * s;    // a01
    gm[tid][4] = -cb * s; gm[tid][5] = sb * s;    // a10
    gm[tid][6] = ca * c;  gm[tid][7] = -sa * c;   // a11
  }
  __syncthreads();

  // ---- phase A: GF(2) evolution, fully unrolled -> registers (fast) ----
  if (tid == 0) {
    unsigned rA[NWIRES], ic[NWIRES];
#pragma unroll
    for (int i = 0; i < NWIRES; i++) { rA[i] = 1u << i; ic[i] = 1u << i; }
#pragma unroll
    for (int lrev = 0; lrev < NLAYERS; lrev++) {
      const int l = NLAYERS - 1 - lrev;
      const int r = (l % (NWIRES - 1)) + 1;
      // inverse ring: same CNOTs, applied w = 9 .. 0
#pragma unroll
      for (int w = NWIRES - 1; w >= 0; w--) {
        const int t = (w + r) % NWIRES;
        rA[9 - t] ^= rA[9 - w];
        ic[9 - w] ^= ic[9 - t];
      }
#pragma unroll
      for (int s = 0; s < 5; s++) {
        const int p1 = 9 - 2 * s, p2 = 8 - 2 * s;
        unsigned u1 = rA[p1], u2 = rA[p2];
        unsigned m1 = ic[p1], m2 = ic[p2];
        // 2-row GF(2) elimination to echelon (b1 in u1 only, b2 in u2 only)
        unsigned b1 = u1 & (0u - u1);
        if (u2 & b1) u2 ^= u1;
        unsigned b2 = u2 & (0u - u2);
        if (u1 & b2) u1 ^= u2;
        const int pid = lrev * 5 + s;
        pp[pid][0] = u1; pp[pid][1] = u2;
        pp[pid][2] = b1; pp[pid][3] = b2;
        plan_idx[pid * 8 + 6] = m1;      // k_main reads P[6], P[7] only
        plan_idx[pid * 8 + 7] = m2;
      }
    }
#pragma unroll
    for (int p = 0; p < NWIRES; p++) plan_final[p] = ic[p];
  } else if (tid >= 100 && tid < 200) {
    // kron matrices in parallel with phase A (needs only gm)
    int t = tid - 100;                 // pass index
    int lrev = t / 5, s = t % 5;
    int l = NLAYERS - 1 - lrev;
    int g1 = l * NWIRES + 2 * s, g2 = g1 + 1;
    float* K = plan_mat + (size_t)t * 64;
#pragma unroll
    for (int r = 0; r < 4; r++) {
#pragma unroll
      for (int c = 0; c < 4; c++) {
        int r1 = r >> 1, c1 = c >> 1, r2 = r & 1, c2 = c & 1;
        float ar = gm[g1][(r1 * 2 + c1) * 2], ai = gm[g1][(r1 * 2 + c1) * 2 + 1];
        float br = gm[g2][(r2 * 2 + c2) * 2], bi = gm[g2][(r2 * 2 + c2) * 2 + 1];
        float kr = ar * br - ai * bi;
        float ki = ar * bi + ai * br;
        float* e = K + (r * 4 + c) * 4;
        e[0] = kr; e[1] = kr; e[2] = -ki; e[3] = ki;   // packed for pk-FMA
      }
    }
  }
  __syncthreads();

  // ---- phase B: bank-uniform basis per pass (100 parallel threads) ----
  if (tid < NPASS) {
    const int pid = tid;
    const unsigned u1 = pp[pid][0], u2 = pp[pid][1];
    const unsigned b1 = pp[pid][2], b2 = pp[pid][3];
    unsigned echPack = 0;              // 4 x 8-bit reduced nibbles
    int cnt = 0, nrem = 0;
    for (int f = 0; f < NWIRES; f++) {
      unsigned ef = 1u << f;
      if (ef == b1 || ef == b2) continue;
      unsigned v = ef ^ (((u1 >> f) & 1u) ? b1 : 0u)
                      ^ (((u2 >> f) & 1u) ? b2 : 0u);
      unsigned n = v & 15u;
#pragma unroll
      for (int rep = 0; rep < 4; rep++) {
#pragma unroll
        for (int k2 = 0; k2 < 4; k2++) {
          unsigned h = (echPack >> (8 * k2)) & 255u;
          if (h) {
            unsigned hb = 0x80000000u >> __clz(h);
            if (n & hb) n ^= h;
          }
        }
      }
      if (n && cnt < 4) {
        echPack |= n << (8 * cnt);
        shb[pid * 8 + cnt] = v;
        cnt++;
      } else {
        shr[pid * 8 + nrem] = v;
        nrem++;
      }
    }
    for (int i = 0; i < nrem; i++) shb[pid * 8 + cnt + i] = shr[pid * 8 + i];
  }
  __syncthreads();

  // ---- phase C: jtab[t][tid] = XOR-select of the ordered basis ----
  for (int t = 0; t < NPASS; t++) {
    unsigned j = 0;
#pragma unroll
    for (int b = 0; b < 8; b++)
      if ((tid >> b) & 1) j ^= shb[t * 8 + b];
    jtab[t * 256 + tid] = j;
  }
}

// ---------------------------------------------------------------------------
// Kernel 2 (fused): blocks 0..783 = usim column p; blocks 784.. = embed rows.
// (r14 verbatim)
// ---------------------------------------------------------------------------
__global__ __launch_bounds__(256) void k_main(const float* __restrict__ plan_mat,
                                              const unsigned* __restrict__ plan_idx,
                                              const unsigned* __restrict__ plan_final,
                                              const unsigned* __restrict__ jtab,
                                              const float* __restrict__ x,
                                              const float* __restrict__ W,
                                              const float* __restrict__ bias,
                                              f16* __restrict__ E,
                                              f16* __restrict__ Bt) {
  __shared__ f32x2 st[DIM];          // usim state (8 KB)
  __shared__ float part[4][NWIRES];  // embed partials
  __shared__ float csh[NWIRES][2];   // embed cos/sin

  const int tid = threadIdx.x;

  if (blockIdx.x < PIXELS) {
    // ---------------- usim: simulate U^dag |col> ----------------
    const int col = blockIdx.x;

    for (int i = tid; i < DIM; i += 256)
      st[i] = (f32x2){i == col ? 1.f : 0.f, 0.f};

    unsigned jn = jtab[tid];           // prefetch pass 0's quad base
    __syncthreads();

    for (int t = 0; t < NPASS; t++) {
      const unsigned* P = plan_idx + (size_t)t * 8;
      const unsigned m1 = P[6], m2 = P[7];
      const f32x4* Kp = (const f32x4*)(plan_mat + (size_t)t * 64);

      const unsigned j = jn;
      if (t + 1 < NPASS) jn = jtab[(t + 1) * 256 + tid];  // hide L2 latency

      f32x2 v0 = st[j];
      f32x2 v1 = st[j ^ m2];
      f32x2 v2 = st[j ^ m1];
      f32x2 v3 = st[j ^ m1 ^ m2];
      f32x2 w0 = {v0.y, v0.x}, w1 = {v1.y, v1.x};
      f32x2 w2 = {v2.y, v2.x}, w3 = {v3.y, v3.x};

      f32x2 r0 = {0.f, 0.f}, r1 = {0.f, 0.f}, r2 = {0.f, 0.f}, r3 = {0.f, 0.f};
      // Kp[e] = (kr, kr, -ki, ki):  acc += (kr,kr)*v ; acc += (-ki,ki)*swap(v)
#define CM(rr, e, vv, ww)                         \
      { f32x4 kk = Kp[e];                         \
        rr += (f32x2){kk.x, kk.y} * (vv);         \
        rr += (f32x2){kk.z, kk.w} * (ww); }
      CM(r0, 0, v0, w0)  CM(r0, 1, v1, w1)  CM(r0, 2, v2, w2)  CM(r0, 3, v3, w3)
      CM(r1, 4, v0, w0)  CM(r1, 5, v1, w1)  CM(r1, 6, v2, w2)  CM(r1, 7, v3, w3)
      CM(r2, 8, v0, w0)  CM(r2, 9, v1, w1)  CM(r2, 10, v2, w2) CM(r2, 11, v3, w3)
      CM(r3, 12, v0, w0) CM(r3, 13, v1, w1) CM(r3, 14, v2, w2) CM(r3, 15, v3, w3)
#undef CM

      // In-place write of the SAME quad this thread read: disjoint across
      // threads, so no intra-pass hazard; one barrier separates passes.
      st[j]           = r0;
      st[j ^ m2]      = r1;
      st[j ^ m1]      = r2;
      st[j ^ m1 ^ m2] = r3;
      __syncthreads();
    }

    // logical amplitude i lives at storage j = XOR of inv columns of set bits;
    // U[p][i] = conj(st[j]).
    unsigned invl[NWIRES];
#pragma unroll
    for (int p = 0; p < NWIRES; p++) invl[p] = plan_final[p];

    __align__(8) f16 re4[4], im4[4];
#pragma unroll
    for (int u = 0; u < 4; u++) {
      int i = tid * 4 + u;
      unsigned j = 0;
#pragma unroll
      for (int p = 0; p < NWIRES; p++)
        if ((i >> p) & 1) j ^= invl[p];
      f32x2 v = st[j];
      re4[u] = (f16)v.x;
      im4[u] = (f16)(-v.y);
    }
    *(uint2*)(&Bt[(size_t)(2 * col) * DIM + tid * 4])     = *(const uint2*)re4;
    *(uint2*)(&Bt[(size_t)(2 * col + 1) * DIM + tid * 4]) = *(const uint2*)im4;
    return;
  }

  // ---------------- embed: linear layer + RY product state ----------------
  const int b = blockIdx.x - PIXELS;
  const float* xr = x + (size_t)b * PIXELS;

  float acc[NWIRES];
#pragma unroll
  for (int w = 0; w < NWIRES; w++) acc[w] = 0.f;

  for (int k = tid; k < PIXELS; k += 256) {
    float xv = xr[k];
#pragma unroll
    for (int w = 0; w < NWIRES; w++) acc[w] = fmaf(xv, W[w * PIXELS + k], acc[w]);
  }

#pragma unroll
  for (int w = 0; w < NWIRES; w++) {
    float v = acc[w];
#pragma unroll
    for (int off = 32; off > 0; off >>= 1) v += __shfl_xor(v, off, 64);
    acc[w] = v;
  }

  const int wv = tid >> 6, ln = tid & 63;
  if (ln == 0) {
#pragma unroll
    for (int w = 0; w < NWIRES; w++) part[wv][w] = acc[w];
  }
  __syncthreads();
  if (tid < NWIRES) {
    float a = part[0][tid] + part[1][tid] + part[2][tid] + part[3][tid] + bias[tid];
    float s, c;
    sincosf(0.5f * a, &s, &c);
    csh[tid][0] = c;
    csh[tid][1] = s;
  }
  __syncthreads();

  __align__(8) f16 e4[4];
#pragma unroll
  for (int u = 0; u < 4; u++) {
    int i = tid * 4 + u;
    float pr = 1.f;
#pragma unroll
    for (int w = 0; w < NWIRES; w++) pr *= csh[w][(i >> (9 - w)) & 1];
    e4[u] = (f16)pr;
  }
  *(uint2*)(&E[(size_t)b * DIM + tid * 4]) = *(const uint2*)e4;
}

// ---------------------------------------------------------------------------
// Kernel 3: C = E[8192][1024] @ Bt^T, f16 MFMA 16x16x32 — 8-phase schedule
// with REGISTER-CACHED fragments (24 unique ds_read_b128 per K-tile per wave):
//   p0 (qm0,qn0): read af<-A-lo (8) + bfl<-B-lo (4); stage B-hi(T+1)
//   p1 (qm0,qn1): read bfh<-B-hi (4), reuse af;      stage A-hi(T+1)
//   p2 (qm1,qn0): read af<-A-hi (8), reuse bfl;      stage A-lo(T+2)
//   p3 (qm1,qn1): NO reads, reuse af+bfh;            stage B-lo(T+2)
//   each phase: barrier -> lgkmcnt(0) -> setprio(1) -> 16 MFMA -> setprio(0)
//   -> [p3: vmcnt(4); T==14: vmcnt(0)] -> barrier.   (r16 ledger unchanged)
// Register audit: acc 128 + af 32 + bfl 16 + bfh 16 + offsets ~20 = ~212.
// T2 swizzle: slot ^= row&7 on stage source + ds_read. XCD swizzle 224=8x28.
// ---------------------------------------------------------------------------
__global__ __launch_bounds__(512, 2) void k_gemm(const f16* __restrict__ E,
                                                 const f16* __restrict__ Bt,
                                                 float* __restrict__ out) {
  __shared__ __align__(16) f16 lds[8][128 * 64];   // 128 KB

  const int tid = threadIdx.x;                     // 0..511
  const int wid = tid >> 6, ln = tid & 63;
  const int wm = wid >> 2, wn = wid & 3;           // 2M x 4N (interleaved)

  const int bid = blockIdx.x;                      // 0..223 (32 mt x 7 nt)
  const int swz = (bid & 7) * 28 + (bid >> 3);     // XCD-contiguous chunks
  const int mt  = swz % 32, nt = swz / 32;
  const int m0  = mt * 256;
  const int n0  = nt * 256;

  f32x4 acc[8][4];
#pragma unroll
  for (int a = 0; a < 8; a++)
#pragma unroll
    for (int q = 0; q < 4; q++) acc[a][q] = (f32x4){0.f, 0.f, 0.f, 0.f};

  // swizzled ds_read offsets within a [128][64] half (same for either half)
  int offA[4][2], offB[2][2];
#pragma unroll
  for (int mi = 0; mi < 4; mi++)
#pragma unroll
    for (int kk = 0; kk < 2; kk++) {
      int r = (mi * 2 + wm) * 16 + (ln & 15);
      offA[mi][kk] = r * 64 + (((kk * 4 + (ln >> 4)) ^ (r & 7)) * 8);
    }
#pragma unroll
  for (int ni = 0; ni < 2; ni++)
#pragma unroll
    for (int kk = 0; kk < 2; kk++) {
      int r = (ni * 4 + wn) * 16 + (ln & 15);
      offB[ni][kk] = r * 64 + (((kk * 4 + (ln >> 4)) ^ (r & 7)) * 8);
    }

  // stage half `half_id` (0=A-lo 1=A-hi 2=B-lo 3=B-hi) of tile `tile`:
  // 2 gload_lds/thread; linear LDS dest, inverse-swizzled global source.
  auto stage = [&](int tile, int half_id) {
    const int buf = tile & 1;
    const f16* src = (half_id < 2) ? E : Bt;
    const int rbase = ((half_id < 2) ? m0 : n0) + ((half_id & 1) ? 128 : 0);
    f16* dst = &lds[buf * 4 + half_id][0];
#pragma unroll
    for (int r2 = 0; r2 < 2; r2++) {
      int u   = r2 * 512 + tid;               // 16B unit, 0..1023
      int row = u >> 3;
      int c8  = (u & 7) ^ (row & 7);          // inverse-swizzled source slot
      gload_lds16((const char*)src +
                      ((size_t)(rbase + row) * 1024 + tile * 64 + c8 * 8) * 2,
                  (char*)dst + (size_t)u * 16);
    }
  };

  // 16 MFMA on quadrant (qm,qn) with fragments in registers
#define MFMAQ(qm, qn, AF, BF)                                                 \
  {                                                                           \
    __builtin_amdgcn_s_setprio(1);                                            \
    _Pragma("unroll")                                                         \
    for (int kk = 0; kk < 2; kk++)                                            \
      _Pragma("unroll")                                                       \
      for (int mi = 0; mi < 4; mi++)                                          \
        _Pragma("unroll")                                                     \
        for (int ni = 0; ni < 2; ni++)                                        \
          acc[(qm) * 4 + mi][(qn) * 2 + ni] =                                 \
              __builtin_amdgcn_mfma_f32_16x16x32_f16(                         \
                  AF[mi][kk], BF[ni][kk],                                     \
                  acc[(qm) * 4 + mi][(qn) * 2 + ni], 0, 0, 0);                \
    __builtin_amdgcn_s_setprio(0);                                            \
  }

  // prologue: tile0 complete + tile1 {A-lo, B-lo}; vmcnt(4) lands tile0.
  stage(0, 0); stage(0, 2); stage(0, 3); stage(0, 1);
  stage(1, 0); stage(1, 2);
  asm volatile("s_waitcnt vmcnt(4)" ::: "memory");
  __builtin_amdgcn_s_barrier();

  for (int T = 0; T < 16; T++) {
    const int buf = T & 1;
    const f16* A_lo = &lds[buf * 4 + 0][0];
    const f16* A_hi = &lds[buf * 4 + 1][0];
    const f16* B_lo = &lds[buf * 4 + 2][0];
    const f16* B_hi = &lds[buf * 4 + 3][0];
    f16x8 af[4][2], bfl[2][2], bfh[2][2];

    // ---- phase 0: (qm0,qn0) — read af(A-lo) + bfl(B-lo) ----
#pragma unroll
    for (int kk = 0; kk < 2; kk++) {
#pragma unroll
      for (int mi = 0; mi < 4; mi++)
        af[mi][kk] = *(const f16x8*)&A_lo[offA[mi][kk]];
#pragma unroll
      for (int ni = 0; ni < 2; ni++)
        bfl[ni][kk] = *(const f16x8*)&B_lo[offB[ni][kk]];
    }
    if (T <= 14) stage(T + 1, 3);
    __builtin_amdgcn_s_barrier();
    asm volatile("s_waitcnt lgkmcnt(0)" ::: "memory");
    MFMAQ(0, 0, af, bfl)
    __builtin_amdgcn_s_barrier();

    // ---- phase 1: (qm0,qn1) — read bfh(B-hi), reuse af ----
#pragma unroll
    for (int kk = 0; kk < 2; kk++)
#pragma unroll
      for (int ni = 0; ni < 2; ni++)
        bfh[ni][kk] = *(const f16x8*)&B_hi[offB[ni][kk]];
    if (T <= 14) stage(T + 1, 1);
    __builtin_amdgcn_s_barrier();
    asm volatile("s_waitcnt lgkmcnt(0)" ::: "memory");
    MFMAQ(0, 1, af, bfh)
    __builtin_amdgcn_s_barrier();

    // ---- phase 2: (qm1,qn0) — read af(A-hi), reuse bfl ----
#pragma unroll
    for (int kk = 0; kk < 2; kk++)
#pragma unroll
      for (int mi = 0; mi < 4; mi++)
        af[mi][kk] = *(const f16x8*)&A_hi[offA[mi][kk]];
    if (T <= 13) stage(T + 2, 0);
    __builtin_amdgcn_s_barrier();
    asm volatile("s_waitcnt lgkmcnt(0)" ::: "memory");
    MFMAQ(1, 0, af, bfl)
    __builtin_amdgcn_s_barrier();

    // ---- phase 3: (qm1,qn1) — no reads, reuse af + bfh ----
    if (T <= 13) stage(T + 2, 2);
    __builtin_amdgcn_s_barrier();
    MFMAQ(1, 1, af, bfh)
    if (T <= 13)      { asm volatile("s_waitcnt vmcnt(4)" ::: "memory"); }
    else if (T == 14) { asm volatile("s_waitcnt vmcnt(0)" ::: "memory"); }
    __builtin_amdgcn_s_barrier();
  }
#undef MFMAQ

  // epilogue: n even = Re, n odd = Im (adjacent lanes); p = n>>1
#pragma unroll
  for (int mig = 0; mig < 8; mig++) {
#pragma unroll
    for (int nig = 0; nig < 4; nig++) {
      int gR = (mig >> 2) * 8 + (mig & 3) * 2 + wm;     // row group 0..15
      int gC = (nig >> 1) * 8 + (nig & 1) * 4 + wn;     // col group 0..15
      int n  = n0 + gC * 16 + (ln & 15);
      int p  = n >> 1;
      bool even = (ln & 1) == 0;
#pragma unroll
      for (int r = 0; r < 4; r++) {
        float v = acc[mig][nig][r];
        float o = __shfl_xor(v, 1, 64);
        if (even && p < PIXELS) {
          int m = m0 + gR * 16 + (ln >> 4) * 4 + r;
          float s2 = (v * v + o * o) * (float)PIXELS;
          out[(size_t)m * PIXELS + p] = fminf(fmaxf(s2, 0.f), 1.f);
        }
      }
    }
  }
}

// ---------------------------------------------------------------------------
extern "C" void kernel_launch(void* const* d_in, const int* in_sizes, int n_in,
                              void* d_out, int out_size, void* d_ws, size_t ws_size,
                              hipStream_t stream) {
  const float* x    = (const float*)d_in[0];
  const float* W    = (const float*)d_in[1];
  const float* bias = (const float*)d_in[2];
  const float* qw   = (const float*)d_in[3];
  float* out        = (float*)d_out;

  char* ws = (char*)d_ws;
  f16* E  = (f16*)(ws);                                   // 16 MiB: [8192][1024]
  f16* Bt = (f16*)(ws + (size_t)16 * 1024 * 1024);        //  4 MiB: [2048][1024]
  float*    plan_mat   = (float*)(ws + (size_t)20 * 1024 * 1024);            // 25.6 KB
  unsigned* plan_idx   = (unsigned*)(ws + (size_t)20 * 1024 * 1024 + 65536); //  3.2 KB
  unsigned* plan_final = (unsigned*)(ws + (size_t)20 * 1024 * 1024 + 131072);//  40 B
  unsigned* jtab       = (unsigned*)(ws + (size_t)20 * 1024 * 1024 + 196608);// 102.4 KB

  k_prep<<<dim3(1), dim3(256), 0, stream>>>(qw, plan_mat, plan_idx, plan_final,
                                            jtab);
  k_main<<<dim3(PIXELS + BATCH), dim3(256), 0, stream>>>(plan_mat, plan_idx,
                                                         plan_final, jtab,
                                                         x, W, bias, E, Bt);
  k_gemm<<<dim3(224), dim3(512), 0, stream>>>(E, Bt, out);
}